// Round 3
// baseline (12905.275 us; speedup 1.0000x reference)
//
#include <hip/hip_runtime.h>

typedef __bf16   bf16x8 __attribute__((ext_vector_type(8)));
typedef float    f32x4  __attribute__((ext_vector_type(4)));
typedef _Float16 f16_t;

#define NB 64
#define NS 512
#define NI 768
#define NH 512

// ---------------- workspace layout (bytes), total ~276.6 MB ----------------
// wiT_h: bf16 [2][2048][768]      @ 0           ( 6,291,456)
// wiT_l: bf16 [2][2048][768]      @ 6291456     ( 6,291,456)
// whT_h: bf16 [2][2048][512]      @ 12582912    ( 4,194,304)
// whT_l: bf16 [2][2048][512]      @ 16777216    ( 4,194,304)
// xp   : f16  [2][32768][2048]    @ 20971520    (268,435,456)
// hbuf : bf16 [2dir][2par][2pt][64][512] @ 289406976 (524,288)
// cnt  : u32  [2][512]            @ 289931264   (4,096)
#define WS_WITH  0L
#define WS_WITL  6291456L
#define WS_WHTH  12582912L
#define WS_WHTL  16777216L
#define WS_XP    20971520L
#define WS_HBUF  289406976L
#define WS_CNT   289931264L

__device__ __forceinline__ float fsig(float x) {
  return __builtin_amdgcn_rcpf(1.f + __builtin_amdgcn_exp2f(-1.442695040888963f * x));
}
__device__ __forceinline__ float ftanh(float x) {
  return 1.f - 2.f * __builtin_amdgcn_rcpf(1.f + __builtin_amdgcn_exp2f(2.885390081777926f * x));
}

// split 8 consecutive LDS floats into hi/lo bf16x8 fragments
__device__ __forceinline__ void split8(const float* p, bf16x8& hi, bf16x8& lo) {
#pragma unroll
  for (int j = 0; j < 8; ++j) {
    float v = p[j];
    __bf16 h = (__bf16)v;
    hi[j] = h;
    lo[j] = (__bf16)(v - (float)h);
  }
}

// ---------------- prep: zero hbuf + counters ----------------
__global__ __launch_bounds__(256) void prep_zero(unsigned int* __restrict__ zr) {
  unsigned wi = blockIdx.x * 256u + threadIdx.x;
  if (wi < 132096u) zr[wi] = 0u;  // hbuf (131072 words) + cnt (1024 words)
}

// ---------------- prep: transpose + split-cast Wi/Wh -> [N][K] bf16 hi+lo ----------------
__global__ __launch_bounds__(256) void transpose_cast(
    const float* __restrict__ Wi_f, const float* __restrict__ Wh_f,
    const float* __restrict__ Wi_b, const float* __restrict__ Wh_b,
    __bf16* __restrict__ wiT_h, __bf16* __restrict__ wiT_l,
    __bf16* __restrict__ whT_h, __bf16* __restrict__ whT_l)
{
  int mat = blockIdx.y;  // 0:Wi_f 1:Wh_f 2:Wi_b 3:Wh_b
  const float* src = (mat == 0) ? Wi_f : (mat == 1) ? Wh_f : (mat == 2) ? Wi_b : Wh_b;
  int K = (mat & 1) ? NH : NI;
  size_t doff = (mat >= 2) ? (size_t)2048 * K : 0;
  __bf16* dh = ((mat & 1) ? whT_h : wiT_h) + doff;
  __bf16* dl = ((mat & 1) ? whT_l : wiT_l) + doff;
  int ntk = K / 32;
  int t = blockIdx.x;
  if (t >= ntk * 64) return;
  int tk = t >> 6, tn = t & 63;
  __shared__ float tb[32][33];
  int tx = threadIdx.x & 31, ty = threadIdx.x >> 5;
#pragma unroll
  for (int i = 0; i < 4; ++i)
    tb[ty + i * 8][tx] = src[(size_t)(tk * 32 + ty + i * 8) * 2048 + tn * 32 + tx];
  __syncthreads();
#pragma unroll
  for (int i = 0; i < 4; ++i) {
    float v = tb[tx][ty + i * 8];
    __bf16 hi = (__bf16)v;
    size_t o = (size_t)(tn * 32 + ty + i * 8) * K + tk * 32 + tx;
    dh[o] = hi;
    dl[o] = (__bf16)(v - (float)hi);
  }
}

// ---------------- phase 1: xp = x @ Wi + (bi + bh), f16 out, 3-term split ----------------
// A staged as raw fp32 (split to hi/lo in registers); B staged as bf16 hi+lo.
__global__ __launch_bounds__(256) void gemm_xproj(
    const float* __restrict__ x,
    const __bf16* __restrict__ wih, const __bf16* __restrict__ wil,
    const float* __restrict__ bi_f, const float* __restrict__ bh_f,
    const float* __restrict__ bi_b, const float* __restrict__ bh_b,
    f16_t* __restrict__ xp)
{
  int dir = blockIdx.y;
  int tm = blockIdx.x >> 4, tn = blockIdx.x & 15;
  const float*  Af = x + (size_t)tm * 128 * NI;
  const __bf16* Bh = wih + (size_t)dir * 2048 * NI + (size_t)tn * 128 * NI;
  const __bf16* Bl = wil + (size_t)dir * 2048 * NI + (size_t)tn * 128 * NI;
  const float* bi = dir ? bi_b : bi_f;
  const float* bh = dir ? bh_b : bh_f;

  __shared__ float  sA[128 * 32];     // 16 KB fp32
  __shared__ __bf16 sBh[128 * 32];    // 8 KB
  __shared__ __bf16 sBl[128 * 32];    // 8 KB
  int tid = threadIdx.x, w = tid >> 6, lane = tid & 63;
  int wm = w >> 1, wn = w & 1;
  int q = lane >> 4, m16 = lane & 15;

  f32x4 acc[4][4] = {};
  for (int kb = 0; kb < NI / 32; ++kb) {
#pragma unroll
    for (int i = 0; i < 4; ++i) {      // A: 1024 16B-chunks (fp32)
      int ch = tid + i * 256;
      int r = ch >> 3, c = ch & 7;     // row, 4-float chunk
      __builtin_amdgcn_global_load_lds(
          (__attribute__((address_space(1))) void*)(Af + (size_t)r * NI + kb * 32 + c * 4),
          (__attribute__((address_space(3))) void*)(sA + ch * 4), 16, 0, 0);
    }
#pragma unroll
    for (int i = 0; i < 2; ++i) {      // B hi/lo: 512 16B-chunks each (bf16)
      int ch = tid + i * 256;
      int r = ch >> 2, c = ch & 3;
      size_t go = (size_t)r * NI + kb * 32 + c * 8;
      __builtin_amdgcn_global_load_lds(
          (__attribute__((address_space(1))) void*)(Bh + go),
          (__attribute__((address_space(3))) void*)(sBh + ch * 8), 16, 0, 0);
      __builtin_amdgcn_global_load_lds(
          (__attribute__((address_space(1))) void*)(Bl + go),
          (__attribute__((address_space(3))) void*)(sBl + ch * 8), 16, 0, 0);
    }
    __syncthreads();
    bf16x8 afh[4], afl[4], bfh[4], bfl[4];
#pragma unroll
    for (int i = 0; i < 4; ++i) {
      split8(sA + (wm * 64 + i * 16 + m16) * 32 + q * 8, afh[i], afl[i]);
      int bo = (wn * 64 + i * 16 + m16) * 32 + q * 8;
      bfh[i] = *(const bf16x8*)(sBh + bo);
      bfl[i] = *(const bf16x8*)(sBl + bo);
    }
#pragma unroll
    for (int mi = 0; mi < 4; ++mi)
#pragma unroll
      for (int ni = 0; ni < 4; ++ni) {
        acc[mi][ni] = __builtin_amdgcn_mfma_f32_16x16x32_bf16(afh[mi], bfh[ni], acc[mi][ni], 0, 0, 0);
        acc[mi][ni] = __builtin_amdgcn_mfma_f32_16x16x32_bf16(afl[mi], bfh[ni], acc[mi][ni], 0, 0, 0);
        acc[mi][ni] = __builtin_amdgcn_mfma_f32_16x16x32_bf16(afh[mi], bfl[ni], acc[mi][ni], 0, 0, 0);
      }
    __syncthreads();
  }
  size_t xpo = (size_t)dir * 32768 * 2048;
#pragma unroll
  for (int ni = 0; ni < 4; ++ni) {
    int n = tn * 128 + wn * 64 + ni * 16 + m16;
    float bias = bi[n] + bh[n];
#pragma unroll
    for (int mi = 0; mi < 4; ++mi) {
#pragma unroll
      for (int r = 0; r < 4; ++r) {
        int m = tm * 128 + wm * 64 + mi * 16 + q * 4 + r;
        xp[xpo + (size_t)m * 2048 + n] = (f16_t)(acc[mi][ni][r] + bias);
      }
    }
  }
}

// ---------------- phase 2: the recurrence (hi/lo split h and Wh) ----------------
// 64 WGs (32/dir), 256 threads. WG (dir,jb) owns h cols [16jb,16jb+16),
// gate cols {g*512+16jb+jj}. Wh_hi/Wh_lo slices in LDS (once). h exchanged as
// bf16 hi+lo via global double buffer + per-step arrival counter.
__global__ __launch_bounds__(256) void lstm_recur(
    const f16_t* __restrict__ xp, const __bf16* __restrict__ whh,
    const __bf16* __restrict__ whl, const float* __restrict__ sent,
    float* __restrict__ out, __bf16* __restrict__ hbuf, unsigned int* __restrict__ cnt)
{
  int dir = blockIdx.x >> 5;
  int jb  = blockIdx.x & 31;
  int tid = threadIdx.x, w = tid >> 6, lane = tid & 63;
  int q = lane >> 4, jj = lane & 15;

  // Row stride 520 bf16 = 1040 B; 520/8=65 odd -> spread across bank groups.
  __shared__ __bf16 wlds_h[64 * 520];
  __shared__ __bf16 wlds_l[64 * 520];
  {
    const __bf16* sh = whh + (size_t)dir * 2048 * NH;
    const __bf16* sl = whl + (size_t)dir * 2048 * NH;
    for (int c = w; c < 64; c += 4) {
      int g = c >> 4, j = c & 15;
      size_t o = (size_t)(g * NH + jb * 16 + j) * NH + lane * 8;
      *(bf16x8*)(wlds_h + c * 520 + lane * 8) = *(const bf16x8*)(sh + o);
      *(bf16x8*)(wlds_l + c * 520 + lane * 8) = *(const bf16x8*)(sl + o);
    }
  }
  __syncthreads();

  float cst[4] = {0.f, 0.f, 0.f, 0.f};
  int b0 = w * 16 + q * 4;
  unsigned int* mycnt = cnt + dir * 512;

  for (int step = 0; step < NS; ++step) {
    int t = dir ? (NS - 1 - step) : step;

    // Prefetch x_proj (acc init) + sentiment: independent of h -> overlaps spin.
    f32x4 acc[4];
    float st[4];
    {
      long xbase = (long)dir * 32768 * 2048 + (long)t * 2048 + jb * 16 + jj;
#pragma unroll
      for (int r = 0; r < 4; ++r) {
        long rowo = (long)(b0 + r) * NS * 2048;
#pragma unroll
        for (int g = 0; g < 4; ++g)
          acc[g][r] = (float)xp[xbase + rowo + (long)g * 512];
        st[r] = sent[(b0 + r) * NS + t];
      }
    }

    if (step) {
      if (tid == 0) {
        while (__hip_atomic_load(mycnt + (step - 1), __ATOMIC_ACQUIRE,
                                 __HIP_MEMORY_SCOPE_AGENT) < 32u)
          __builtin_amdgcn_s_sleep(1);
      }
      __syncthreads();
      __threadfence();  // acquire + L1 invalidate before reading fresh h
    }

    size_t rb = (size_t)(dir * 2 + (step & 1)) * 2 * 64 * NH;
    size_t wb = (size_t)(dir * 2 + ((step & 1) ^ 1)) * 2 * 64 * NH;
    const __bf16* hrd_h = hbuf + rb;
    const __bf16* hrd_l = hbuf + rb + 64 * NH;
    __bf16* hwr_h = hbuf + wb;
    __bf16* hwr_l = hbuf + wb + 64 * NH;

    // gates[64x64] += (h_hi + h_lo) @ (Wh_hi + Wh_lo)  [3 terms]
    const __bf16* arow_h = hrd_h + (size_t)(w * 16 + jj) * NH + q * 8;
    const __bf16* arow_l = hrd_l + (size_t)(w * 16 + jj) * NH + q * 8;
#pragma unroll
    for (int kb = 0; kb < 16; ++kb) {
      bf16x8 a_h = *(const bf16x8*)(arow_h + kb * 32);
      bf16x8 a_l = *(const bf16x8*)(arow_l + kb * 32);
#pragma unroll
      for (int g = 0; g < 4; ++g) {
        int bo = (g * 16 + jj) * 520 + kb * 32 + q * 8;
        bf16x8 b_h = *(const bf16x8*)(wlds_h + bo);
        bf16x8 b_l = *(const bf16x8*)(wlds_l + bo);
        acc[g] = __builtin_amdgcn_mfma_f32_16x16x32_bf16(a_h, b_h, acc[g], 0, 0, 0);
        acc[g] = __builtin_amdgcn_mfma_f32_16x16x32_bf16(a_l, b_h, acc[g], 0, 0, 0);
        acc[g] = __builtin_amdgcn_mfma_f32_16x16x32_bf16(a_h, b_l, acc[g], 0, 0, 0);
      }
    }

    // elementwise: lane owns (b0+r, jj)
#pragma unroll
    for (int r = 0; r < 4; ++r) {
      int b = b0 + r;
      float it = fsig(acc[0][r]) * st[r];
      float ft = fsig(acc[1][r]) * (1.f + st[r]);
      float gt = ftanh(acc[2][r]);
      float ot = fsig(acc[3][r]);
      float cv = ft * cst[r] + it * gt;
      cst[r] = cv;
      float h = ot * ftanh(cv);
      out[((long)b * NS + t) * 1024 + dir * 512 + jb * 16 + jj] = h;
      __bf16 hh = (__bf16)h;
      hwr_h[(size_t)b * NH + jb * 16 + jj] = hh;
      hwr_l[(size_t)b * NH + jb * 16 + jj] = (__bf16)(h - (float)hh);
    }

    __threadfence();   // release h writes device-wide
    __syncthreads();
    if (tid == 0)
      __hip_atomic_fetch_add(mycnt + step, 1u, __ATOMIC_RELEASE, __HIP_MEMORY_SCOPE_AGENT);
  }
}

extern "C" void kernel_launch(void* const* d_in, const int* in_sizes, int n_in,
                              void* d_out, int out_size, void* d_ws, size_t ws_size,
                              hipStream_t stream) {
  const float* x    = (const float*)d_in[0];
  const float* sent = (const float*)d_in[1];
  const float* Wi_f = (const float*)d_in[2];
  const float* bi_f = (const float*)d_in[3];
  const float* Wh_f = (const float*)d_in[4];
  const float* bh_f = (const float*)d_in[5];
  const float* Wi_b = (const float*)d_in[6];
  const float* bi_b = (const float*)d_in[7];
  const float* Wh_b = (const float*)d_in[8];
  const float* bh_b = (const float*)d_in[9];

  char* ws = (char*)d_ws;
  __bf16*       wiT_h = (__bf16*)(ws + WS_WITH);
  __bf16*       wiT_l = (__bf16*)(ws + WS_WITL);
  __bf16*       whT_h = (__bf16*)(ws + WS_WHTH);
  __bf16*       whT_l = (__bf16*)(ws + WS_WHTL);
  f16_t*        xp    = (f16_t*)(ws + WS_XP);
  __bf16*       hbuf  = (__bf16*)(ws + WS_HBUF);
  unsigned int* cnt   = (unsigned int*)(ws + WS_CNT);
  unsigned int* zr    = (unsigned int*)(ws + WS_HBUF);  // hbuf+cnt contiguous

  prep_zero<<<dim3(517), dim3(256), 0, stream>>>(zr);
  transpose_cast<<<dim3(1536, 4), dim3(256), 0, stream>>>(
      Wi_f, Wh_f, Wi_b, Wh_b, wiT_h, wiT_l, whT_h, whT_l);
  gemm_xproj<<<dim3(4096, 2), dim3(256), 0, stream>>>(
      x, wiT_h, wiT_l, bi_f, bh_f, bi_b, bh_b, xp);
  lstm_recur<<<dim3(64), dim3(256), 0, stream>>>(
      xp, whT_h, whT_l, sent, (float*)d_out, hbuf, cnt);
}

// Round 4
// 8647.823 us; speedup vs baseline: 1.4923x; 1.4923x over previous
//
#include <hip/hip_runtime.h>

typedef __bf16   bf16x8 __attribute__((ext_vector_type(8)));
typedef float    f32x4  __attribute__((ext_vector_type(4)));
typedef _Float16 f16_t;

#define NB 64
#define NS 512
#define NI 768
#define NH 512

// ---------------- workspace layout (bytes), total ~276.6 MB ----------------
// wiT_h: bf16 [2][2048][768]      @ 0           ( 6,291,456)
// wiT_l: bf16 [2][2048][768]      @ 6291456     ( 6,291,456)
// whT_h: bf16 [2][2048][512]      @ 12582912    ( 4,194,304)
// whT_l: bf16 [2][2048][512]      @ 16777216    ( 4,194,304)
// xp   : f16  [2][32][512][64][64] @ 20971520   (268,435,456)  (dir,jb,t,b,g*16+jj)
// hpk  : u32  [2dir][2par][64][512] @ 289406976 (524,288)      (hi<<16|lo per elem)
// cnt  : u32  [2][512]            @ 289931264   (4,096)
#define WS_WITH  0L
#define WS_WITL  6291456L
#define WS_WHTH  12582912L
#define WS_WHTL  16777216L
#define WS_XP    20971520L
#define WS_HPK   289406976L
#define WS_CNT   289931264L

__device__ __forceinline__ float fsig(float x) {
  return __builtin_amdgcn_rcpf(1.f + __builtin_amdgcn_exp2f(-1.442695040888963f * x));
}
__device__ __forceinline__ float ftanh(float x) {
  return 1.f - 2.f * __builtin_amdgcn_rcpf(1.f + __builtin_amdgcn_exp2f(2.885390081777926f * x));
}

// split 8 consecutive LDS floats into hi/lo bf16x8 fragments
__device__ __forceinline__ void split8(const float* p, bf16x8& hi, bf16x8& lo) {
#pragma unroll
  for (int j = 0; j < 8; ++j) {
    float v = p[j];
    __bf16 h = (__bf16)v;
    hi[j] = h;
    lo[j] = (__bf16)(v - (float)h);
  }
}

// load 8 packed (hi<<16|lo) u32 h-elements via coherent agent-scope atomics,
// unpack to hi/lo bf16x8 with v_perm.
__device__ __forceinline__ void loadA16(const unsigned int* p, bf16x8& hi, bf16x8& lo) {
  unsigned long long q0 = __hip_atomic_load((const unsigned long long*)(p + 0),
                                            __ATOMIC_RELAXED, __HIP_MEMORY_SCOPE_AGENT);
  unsigned long long q1 = __hip_atomic_load((const unsigned long long*)(p + 2),
                                            __ATOMIC_RELAXED, __HIP_MEMORY_SCOPE_AGENT);
  unsigned long long q2 = __hip_atomic_load((const unsigned long long*)(p + 4),
                                            __ATOMIC_RELAXED, __HIP_MEMORY_SCOPE_AGENT);
  unsigned long long q3 = __hip_atomic_load((const unsigned long long*)(p + 6),
                                            __ATOMIC_RELAXED, __HIP_MEMORY_SCOPE_AGENT);
  unsigned a0 = (unsigned)q0, a1 = (unsigned)(q0 >> 32);
  unsigned a2 = (unsigned)q1, a3 = (unsigned)(q1 >> 32);
  unsigned a4 = (unsigned)q2, a5 = (unsigned)(q2 >> 32);
  unsigned a6 = (unsigned)q3, a7 = (unsigned)(q3 >> 32);
  union { unsigned u[4]; bf16x8 v; } H, L;
  H.u[0] = __builtin_amdgcn_perm(a1, a0, 0x07060302);
  H.u[1] = __builtin_amdgcn_perm(a3, a2, 0x07060302);
  H.u[2] = __builtin_amdgcn_perm(a5, a4, 0x07060302);
  H.u[3] = __builtin_amdgcn_perm(a7, a6, 0x07060302);
  L.u[0] = __builtin_amdgcn_perm(a1, a0, 0x05040100);
  L.u[1] = __builtin_amdgcn_perm(a3, a2, 0x05040100);
  L.u[2] = __builtin_amdgcn_perm(a5, a4, 0x05040100);
  L.u[3] = __builtin_amdgcn_perm(a7, a6, 0x05040100);
  hi = H.v; lo = L.v;
}

// ---------------- prep: zero hpk + counters ----------------
__global__ __launch_bounds__(256) void prep_zero(unsigned int* __restrict__ zr) {
  unsigned wi = blockIdx.x * 256u + threadIdx.x;
  if (wi < 132096u) zr[wi] = 0u;  // hpk (131072 words) + cnt (1024 words)
}

// ---------------- prep: transpose + split-cast Wi/Wh -> [N][K] bf16 hi+lo ----------------
__global__ __launch_bounds__(256) void transpose_cast(
    const float* __restrict__ Wi_f, const float* __restrict__ Wh_f,
    const float* __restrict__ Wi_b, const float* __restrict__ Wh_b,
    __bf16* __restrict__ wiT_h, __bf16* __restrict__ wiT_l,
    __bf16* __restrict__ whT_h, __bf16* __restrict__ whT_l)
{
  int mat = blockIdx.y;  // 0:Wi_f 1:Wh_f 2:Wi_b 3:Wh_b
  const float* src = (mat == 0) ? Wi_f : (mat == 1) ? Wh_f : (mat == 2) ? Wi_b : Wh_b;
  int K = (mat & 1) ? NH : NI;
  size_t doff = (mat >= 2) ? (size_t)2048 * K : 0;
  __bf16* dh = ((mat & 1) ? whT_h : wiT_h) + doff;
  __bf16* dl = ((mat & 1) ? whT_l : wiT_l) + doff;
  int ntk = K / 32;
  int t = blockIdx.x;
  if (t >= ntk * 64) return;
  int tk = t >> 6, tn = t & 63;
  __shared__ float tb[32][33];
  int tx = threadIdx.x & 31, ty = threadIdx.x >> 5;
#pragma unroll
  for (int i = 0; i < 4; ++i)
    tb[ty + i * 8][tx] = src[(size_t)(tk * 32 + ty + i * 8) * 2048 + tn * 32 + tx];
  __syncthreads();
#pragma unroll
  for (int i = 0; i < 4; ++i) {
    float v = tb[tx][ty + i * 8];
    __bf16 hi = (__bf16)v;
    size_t o = (size_t)(tn * 32 + ty + i * 8) * K + tk * 32 + tx;
    dh[o] = hi;
    dl[o] = (__bf16)(v - (float)hi);
  }
}

// ---------------- phase 1: xp = x @ Wi + (bi + bh), f16 out, 3-term split ----------------
// Output in recurrence-friendly layout: xp[dir][jb][t][b][g*16+jj].
__global__ __launch_bounds__(256) void gemm_xproj(
    const float* __restrict__ x,
    const __bf16* __restrict__ wih, const __bf16* __restrict__ wil,
    const float* __restrict__ bi_f, const float* __restrict__ bh_f,
    const float* __restrict__ bi_b, const float* __restrict__ bh_b,
    f16_t* __restrict__ xp)
{
  int dir = blockIdx.y;
  int tm = blockIdx.x >> 4, tn = blockIdx.x & 15;
  const float*  Af = x + (size_t)tm * 128 * NI;
  const __bf16* Bh = wih + (size_t)dir * 2048 * NI + (size_t)tn * 128 * NI;
  const __bf16* Bl = wil + (size_t)dir * 2048 * NI + (size_t)tn * 128 * NI;
  const float* bi = dir ? bi_b : bi_f;
  const float* bh = dir ? bh_b : bh_f;

  __shared__ float  sA[128 * 32];
  __shared__ __bf16 sBh[128 * 32];
  __shared__ __bf16 sBl[128 * 32];
  int tid = threadIdx.x, w = tid >> 6, lane = tid & 63;
  int wm = w >> 1, wn = w & 1;
  int q = lane >> 4, m16 = lane & 15;

  f32x4 acc[4][4] = {};
  for (int kb = 0; kb < NI / 32; ++kb) {
#pragma unroll
    for (int i = 0; i < 4; ++i) {
      int ch = tid + i * 256;
      int r = ch >> 3, c = ch & 7;
      __builtin_amdgcn_global_load_lds(
          (__attribute__((address_space(1))) void*)(Af + (size_t)r * NI + kb * 32 + c * 4),
          (__attribute__((address_space(3))) void*)(sA + ch * 4), 16, 0, 0);
    }
#pragma unroll
    for (int i = 0; i < 2; ++i) {
      int ch = tid + i * 256;
      int r = ch >> 2, c = ch & 3;
      size_t go = (size_t)r * NI + kb * 32 + c * 8;
      __builtin_amdgcn_global_load_lds(
          (__attribute__((address_space(1))) void*)(Bh + go),
          (__attribute__((address_space(3))) void*)(sBh + ch * 8), 16, 0, 0);
      __builtin_amdgcn_global_load_lds(
          (__attribute__((address_space(1))) void*)(Bl + go),
          (__attribute__((address_space(3))) void*)(sBl + ch * 8), 16, 0, 0);
    }
    __syncthreads();
    bf16x8 afh[4], afl[4], bfh[4], bfl[4];
#pragma unroll
    for (int i = 0; i < 4; ++i) {
      split8(sA + (wm * 64 + i * 16 + m16) * 32 + q * 8, afh[i], afl[i]);
      int bo = (wn * 64 + i * 16 + m16) * 32 + q * 8;
      bfh[i] = *(const bf16x8*)(sBh + bo);
      bfl[i] = *(const bf16x8*)(sBl + bo);
    }
#pragma unroll
    for (int mi = 0; mi < 4; ++mi)
#pragma unroll
      for (int ni = 0; ni < 4; ++ni) {
        acc[mi][ni] = __builtin_amdgcn_mfma_f32_16x16x32_bf16(afh[mi], bfh[ni], acc[mi][ni], 0, 0, 0);
        acc[mi][ni] = __builtin_amdgcn_mfma_f32_16x16x32_bf16(afl[mi], bfh[ni], acc[mi][ni], 0, 0, 0);
        acc[mi][ni] = __builtin_amdgcn_mfma_f32_16x16x32_bf16(afh[mi], bfl[ni], acc[mi][ni], 0, 0, 0);
      }
    __syncthreads();
  }
#pragma unroll
  for (int ni = 0; ni < 4; ++ni) {
    int n = tn * 128 + wn * 64 + ni * 16 + m16;
    int g = n >> 9, jbx = (n >> 4) & 31, jjx = n & 15;
    float bias = bi[n] + bh[n];
    size_t nbase = ((size_t)(dir * 32 + jbx) * 512) * 4096 + g * 16 + jjx;
#pragma unroll
    for (int mi = 0; mi < 4; ++mi) {
#pragma unroll
      for (int r = 0; r < 4; ++r) {
        int m = tm * 128 + wm * 64 + mi * 16 + q * 4 + r;
        int b = m >> 9, t = m & 511;
        xp[nbase + (size_t)t * 4096 + b * 64] = (f16_t)(acc[mi][ni][r] + bias);
      }
    }
  }
}

// ---------------- phase 2: recurrence, fence-free coherent exchange ----------------
// 64 WGs (32/dir), 256 threads, 1 WG/CU. WG (dir,jb) owns h cols [16jb,16jb+16).
// Wave w owns k-slice [128w,128w+128): Wh hi/lo fragments live in VGPRs (loaded
// once). Per step: coherent u32-atomic loads of packed h from LLC, 192 MFMAs of
// k-partials, cross-wave reduce through lane-indexed LDS, elementwise, coherent
// packed h store, counter handshake (relaxed agent atomics; __syncthreads drains
// vmcnt so data is at the coherent point before the flag increments).
__global__ __launch_bounds__(256, 1) void lstm_recur(
    const f16_t* __restrict__ xp, const __bf16* __restrict__ whh,
    const __bf16* __restrict__ whl, const float* __restrict__ sent,
    float* __restrict__ out, unsigned int* __restrict__ hpk,
    unsigned int* __restrict__ cnt)
{
  int dir = blockIdx.x >> 5;
  int jb  = blockIdx.x & 31;
  int tid = threadIdx.x, w = tid >> 6, lane = tid & 63;
  int q = lane >> 4, jj = lane & 15;

  // B fragments (step-invariant) -> registers. [g][kb], k = w*128+kb*32+q*8+i.
  bf16x8 bh_r[4][4], bl_r[4][4];
  {
    const __bf16* sh = whh + (size_t)dir * 2048 * NH;
    const __bf16* sl = whl + (size_t)dir * 2048 * NH;
#pragma unroll
    for (int g = 0; g < 4; ++g) {
      size_t nrow = (size_t)(g * NH + jb * 16 + jj) * NH + w * 128 + q * 8;
#pragma unroll
      for (int kb = 0; kb < 4; ++kb) {
        bh_r[g][kb] = *(const bf16x8*)(sh + nrow + kb * 32);
        bl_r[g][kb] = *(const bf16x8*)(sl + nrow + kb * 32);
      }
    }
  }

  __shared__ f32x4 pbuf[4][4][4][64];  // [src_wave][mi][g][lane], 64 KB

  float cst[4] = {0.f, 0.f, 0.f, 0.f};
  unsigned int* mycnt = cnt + dir * 512;
  const f16_t* xslab = xp + ((size_t)(dir * 32 + jb) * 512) * 4096;

  for (int step = 0; step < NS; ++step) {
    int t = dir ? (NS - 1 - step) : step;

    // xp + sentiment prefetch (independent of h -> overlaps spin)
    float xg[4][4];  // [g][r]
    float st[4];
    {
      const f16_t* xrow = xslab + (size_t)t * 4096;
#pragma unroll
      for (int r = 0; r < 4; ++r) {
        int b = w * 16 + q * 4 + r;
#pragma unroll
        for (int g = 0; g < 4; ++g)
          xg[g][r] = (float)xrow[b * 64 + g * 16 + jj];
        st[r] = sent[b * NS + t];
      }
    }

    // handshake: wait for all 32 WGs of this dir to publish h(step)
    if (step) {
      while (__hip_atomic_load(mycnt + (step - 1), __ATOMIC_RELAXED,
                               __HIP_MEMORY_SCOPE_AGENT) < 32u)
        __builtin_amdgcn_s_sleep(1);
    }

    const unsigned int* hrd = hpk + (size_t)(dir * 2 + (step & 1)) * 64 * NH;
    unsigned int*       hwr = hpk + (size_t)(dir * 2 + ((step & 1) ^ 1)) * 64 * NH;

    f32x4 acc[4][4] = {};  // [mi][g] k-partials for this wave's slice
    if (step) {
      bf16x8 Ah[2][4], Al[2][4];
      const unsigned int* abase = hrd + (size_t)jj * NH + w * 128 + q * 8;
#pragma unroll
      for (int kb = 0; kb < 4; ++kb)
        loadA16(abase + kb * 32, Ah[0][kb], Al[0][kb]);
#pragma unroll
      for (int mi = 0; mi < 4; ++mi) {
        int cur = mi & 1;
        if (mi < 3) {
          const unsigned int* nb = abase + (size_t)(mi + 1) * 16 * NH;
#pragma unroll
          for (int kb = 0; kb < 4; ++kb)
            loadA16(nb + kb * 32, Ah[cur ^ 1][kb], Al[cur ^ 1][kb]);
        }
#pragma unroll
        for (int kb = 0; kb < 4; ++kb)
#pragma unroll
          for (int g = 0; g < 4; ++g) {
            acc[mi][g] = __builtin_amdgcn_mfma_f32_16x16x32_bf16(Ah[cur][kb], bh_r[g][kb], acc[mi][g], 0, 0, 0);
            acc[mi][g] = __builtin_amdgcn_mfma_f32_16x16x32_bf16(Al[cur][kb], bh_r[g][kb], acc[mi][g], 0, 0, 0);
            acc[mi][g] = __builtin_amdgcn_mfma_f32_16x16x32_bf16(Ah[cur][kb], bl_r[g][kb], acc[mi][g], 0, 0, 0);
          }
      }
    }

    // cross-wave k-reduction through LDS (lane-indexed b128, conflict-free)
#pragma unroll
    for (int mi = 0; mi < 4; ++mi)
      if (mi != w)
#pragma unroll
        for (int g = 0; g < 4; ++g) pbuf[w][mi][g][lane] = acc[mi][g];
    __syncthreads();
    f32x4 gates[4];
#pragma unroll
    for (int g = 0; g < 4; ++g) gates[g] = acc[w][g];
#pragma unroll
    for (int w2 = 0; w2 < 4; ++w2)
      if (w2 != w)
#pragma unroll
        for (int g = 0; g < 4; ++g) gates[g] += pbuf[w2][w][g][lane];

    // elementwise: lane owns (b = w*16+q*4+r, jj)
#pragma unroll
    for (int r = 0; r < 4; ++r) {
      int b = w * 16 + q * 4 + r;
      float it = fsig(gates[0][r] + xg[0][r]) * st[r];
      float ft = fsig(gates[1][r] + xg[1][r]) * (1.f + st[r]);
      float gt = ftanh(gates[2][r] + xg[2][r]);
      float ot = fsig(gates[3][r] + xg[3][r]);
      float cv = ft * cst[r] + it * gt;
      cst[r] = cv;
      float h = ot * ftanh(cv);
      out[((long)b * NS + t) * 1024 + dir * 512 + jb * 16 + jj] = h;
      __bf16 h_hi = (__bf16)h;
      __bf16 h_lo = (__bf16)(h - (float)h_hi);
      unsigned pk = ((unsigned)__builtin_bit_cast(unsigned short, h_hi) << 16)
                  | (unsigned)__builtin_bit_cast(unsigned short, h_lo);
      __hip_atomic_store(hwr + (size_t)b * NH + jb * 16 + jj, pk,
                         __ATOMIC_RELAXED, __HIP_MEMORY_SCOPE_AGENT);
    }

    // barrier drains vmcnt(0): h stores are at the coherent point; then flag.
    __syncthreads();
    if (tid == 0)
      __hip_atomic_fetch_add(mycnt + step, 1u, __ATOMIC_RELAXED, __HIP_MEMORY_SCOPE_AGENT);
  }
}

extern "C" void kernel_launch(void* const* d_in, const int* in_sizes, int n_in,
                              void* d_out, int out_size, void* d_ws, size_t ws_size,
                              hipStream_t stream) {
  const float* x    = (const float*)d_in[0];
  const float* sent = (const float*)d_in[1];
  const float* Wi_f = (const float*)d_in[2];
  const float* bi_f = (const float*)d_in[3];
  const float* Wh_f = (const float*)d_in[4];
  const float* bh_f = (const float*)d_in[5];
  const float* Wi_b = (const float*)d_in[6];
  const float* bi_b = (const float*)d_in[7];
  const float* Wh_b = (const float*)d_in[8];
  const float* bh_b = (const float*)d_in[9];

  char* ws = (char*)d_ws;
  __bf16*       wiT_h = (__bf16*)(ws + WS_WITH);
  __bf16*       wiT_l = (__bf16*)(ws + WS_WITL);
  __bf16*       whT_h = (__bf16*)(ws + WS_WHTH);
  __bf16*       whT_l = (__bf16*)(ws + WS_WHTL);
  f16_t*        xp    = (f16_t*)(ws + WS_XP);
  unsigned int* hpk   = (unsigned int*)(ws + WS_HPK);
  unsigned int* cnt   = (unsigned int*)(ws + WS_CNT);
  unsigned int* zr    = (unsigned int*)(ws + WS_HPK);  // hpk+cnt contiguous

  prep_zero<<<dim3(517), dim3(256), 0, stream>>>(zr);
  transpose_cast<<<dim3(1536, 4), dim3(256), 0, stream>>>(
      Wi_f, Wh_f, Wi_b, Wh_b, wiT_h, wiT_l, whT_h, whT_l);
  gemm_xproj<<<dim3(4096, 2), dim3(256), 0, stream>>>(
      x, wiT_h, wiT_l, bi_f, bh_f, bi_b, bh_b, xp);
  lstm_recur<<<dim3(64), dim3(256), 0, stream>>>(
      xp, whT_h, whT_l, sent, (float*)d_out, hpk, cnt);
}